// Round 5
// baseline (259.309 us; speedup 1.0000x reference)
//
#include <hip/hip_runtime.h>
#include <math.h>

#define L_SEQ 32768
#define SMD 132   // dword stride of LDS matrices (132%32=4 -> 2-way conflicts only)

typedef float f32x4 __attribute__((ext_vector_type(4)));
typedef short bf16x8 __attribute__((ext_vector_type(8)));

__device__ __forceinline__ unsigned short f2bf(float x) {
  unsigned u = __float_as_uint(x);
  u = u + 0x7FFFu + ((u >> 16) & 1u);
  return (unsigned short)(u >> 16);
}
__device__ __forceinline__ float bf2f(unsigned short h) {
  return __uint_as_float(((unsigned)h) << 16);
}
// pack f32 -> dword (lo16<<16 | hi16), value ~= hi + lo
__device__ __forceinline__ unsigned packhl(float v) {
  unsigned short h = f2bf(v);
  unsigned short l = f2bf(v - bf2f(h));
  return ((unsigned)l << 16) | (unsigned)h;
}
__device__ __forceinline__ float unpackhl(unsigned d) {
  return bf2f((unsigned short)d) + bf2f((unsigned short)(d >> 16));
}
__device__ __forceinline__ bf16x8 exHi(uint4 q0, uint4 q1) {
  union { unsigned d[4]; bf16x8 v; } u;
  u.d[0] = (q0.y << 16) | (q0.x & 0xffffu);
  u.d[1] = (q0.w << 16) | (q0.z & 0xffffu);
  u.d[2] = (q1.y << 16) | (q1.x & 0xffffu);
  u.d[3] = (q1.w << 16) | (q1.z & 0xffffu);
  return u.v;
}
__device__ __forceinline__ bf16x8 exLo(uint4 q0, uint4 q1) {
  union { unsigned d[4]; bf16x8 v; } u;
  u.d[0] = (q0.y & 0xffff0000u) | (q0.x >> 16);
  u.d[1] = (q0.w & 0xffff0000u) | (q0.z >> 16);
  u.d[2] = (q1.y & 0xffff0000u) | (q1.x >> 16);
  u.d[3] = (q1.w & 0xffff0000u) | (q1.z >> 16);
  return u.v;
}

// ---------------------------------------------------------------------------
// out = epi( A(128x128) * B(128xN) ), Mrows rows of output used.
// A-frags: row-major reads (LDS M, or global packed rows). B-frags: reads of
// a TRANSPOSED copy (LDS Bt, or global Rt rows). fp32 emulated by 3 bf16
// MFMAs (hh+hl+lh). Fragment scheme identical to round-2's verified kernel.
// ASRC: 0 = LDS M | 1 = global packed rows (gA, stride 128, zero if row>=Mrows)
// BSRC: 0 = LDS Bt | 1 = global packed rows = cols of B (gB, stride 128, zero if col>=N)
// OUT : 0 = LDS M in-place | 1 = global transposed uint4 (gO[(obase+c)*ldo+r])
//       2 = global rows scalar (gO[(obase+r)*128+c], r<Mrows)
// MODE: 0 none | 2 v+=E1+E2+I with E1=M[r][c], E2=Bt[c][r] | 3 v=c3*v-I
// Two internal __syncthreads: entry (operand readiness) and pre-epilogue
// (all reads drained before in-place writes). ALL threads reach both.
// ---------------------------------------------------------------------------
template<int ASRC, int BSRC, int OUT, int MODE>
__device__ void mm(unsigned* Ml, unsigned* Bt,
                   const unsigned* gA, const unsigned* gB,
                   unsigned* gO, int obase, int ldo,
                   int Mrows, int N, float c3) {
  const int t = threadIdx.x;
  const int lane = t & 63;
  const int la = lane & 15, g = lane >> 4;
  const int r0 = (t >> 6) << 5;
  const int fcn = (N + 15) >> 4;
  const bool act = (r0 < Mrows);
  __syncthreads();
  f32x4 acc[2][8];
#pragma unroll
  for (int a = 0; a < 2; ++a)
#pragma unroll
    for (int b = 0; b < 8; ++b) acc[a][b] = (f32x4){0.f, 0.f, 0.f, 0.f};
  if (act) {
#pragma unroll
    for (int kb = 0; kb < 4; ++kb) {
      const int k0 = (kb << 5) + (g << 3);
      bf16x8 Ah[2], Al[2];
#pragma unroll
      for (int fr = 0; fr < 2; ++fr) {
        int ar = r0 + (fr << 4) + la;
        uint4 q0 = make_uint4(0, 0, 0, 0), q1 = q0;
        if (ASRC == 0) {
          const uint4* p = (const uint4*)(Ml + ar * SMD + k0);
          q0 = p[0]; q1 = p[1];
        } else if (ar < Mrows) {
          const uint4* p = (const uint4*)(gA + ar * 128 + k0);
          q0 = p[0]; q1 = p[1];
        }
        Ah[fr] = exHi(q0, q1);
        Al[fr] = exLo(q0, q1);
      }
#pragma unroll
      for (int fc = 0; fc < 8; ++fc) if (fc < fcn) {
        int c = (fc << 4) + la;
        uint4 q0 = make_uint4(0, 0, 0, 0), q1 = q0;
        if (BSRC == 0) {
          const uint4* p = (const uint4*)(Bt + c * SMD + k0);
          q0 = p[0]; q1 = p[1];
        } else if (c < N) {
          const uint4* p = (const uint4*)(gB + c * 128 + k0);
          q0 = p[0]; q1 = p[1];
        }
        bf16x8 Bh = exHi(q0, q1), Bl = exLo(q0, q1);
#pragma unroll
        for (int fr = 0; fr < 2; ++fr) if (r0 + (fr << 4) < Mrows) {
          acc[fr][fc] = __builtin_amdgcn_mfma_f32_16x16x32_bf16(Ah[fr], Bh, acc[fr][fc], 0, 0, 0);
          acc[fr][fc] = __builtin_amdgcn_mfma_f32_16x16x32_bf16(Ah[fr], Bl, acc[fr][fc], 0, 0, 0);
          acc[fr][fc] = __builtin_amdgcn_mfma_f32_16x16x32_bf16(Al[fr], Bh, acc[fr][fc], 0, 0, 0);
        }
      }
    }
  }
  __syncthreads();   // all operand reads done -> in-place writes safe
  if (act) {
#pragma unroll
    for (int fr = 0; fr < 2; ++fr) if (r0 + (fr << 4) < Mrows)
#pragma unroll
      for (int fc = 0; fc < 8; ++fc) if (fc < fcn) {
        int rbase = r0 + (fr << 4) + (g << 2);
        int cc = (fc << 4) + la;
        unsigned dw[4];
#pragma unroll
        for (int j = 0; j < 4; ++j) {
          int rr = rbase + j;
          float v = acc[fr][fc][j];
          if (MODE == 2)
            v += unpackhl(Ml[rr * SMD + cc]) + unpackhl(Bt[cc * SMD + rr]) +
                 ((rr == cc) ? 1.f : 0.f);
          if (MODE == 3) v = c3 * v - ((rr == cc) ? 1.f : 0.f);
          dw[j] = packhl(v);
        }
        if (OUT == 0) {
#pragma unroll
          for (int j = 0; j < 4; ++j) Ml[(rbase + j) * SMD + cc] = dw[j];
        } else if (OUT == 1) {
          if (cc < N)
            *(uint4*)(gO + (obase + cc) * ldo + rbase) =
                make_uint4(dw[0], dw[1], dw[2], dw[3]);
        } else {
#pragma unroll
          for (int j = 0; j < 4; ++j)
            if (rbase + j < Mrows) gO[(obase + rbase + j) * 128 + cc] = dw[j];
        }
      }
  }
}

// Bt[c][k] = M[k][c]; both strides SMD. 2-way-conflict-free reads and writes.
__device__ __forceinline__ void transposeMB(const unsigned* Ml, unsigned* Bt) {
  __syncthreads();
  const int t = threadIdx.x;
  const int c = t & 127;
  const int kb = (t >> 7) << 6;
#pragma unroll
  for (int k = 0; k < 64; ++k)
    Bt[c * SMD + kb + k] = Ml[(kb + k) * SMD + c];
}

// ---------------------------------------------------------------------------
// Chain kernel: 2 independent blocks, each LDS-resident (M + Bt, 132KB).
// Both duplicate Neumann->ab; block 0 builds Rt (256x128), block 1 builds S.
// All products commute (polynomials in T) so operand order always fits the
// (row-major A, transposed B) layouts.
// ---------------------------------------------------------------------------
__global__ void __launch_bounds__(256, 1) chain2(const float* __restrict__ A,
                                                 const float* __restrict__ Bv,
                                                 const float* __restrict__ Cv,
                                                 const float* __restrict__ lstep,
                                                 unsigned* wsdw) {
  extern __shared__ unsigned lds[];
  unsigned* Ml = lds;
  unsigned* Bt = lds + 128 * SMD;
  unsigned* gU12t = wsdw + blockIdx.x * (128 * SMD);
  unsigned* Rt = wsdw + 2 * 128 * SMD;   // 256 x 128 packed dwords
  unsigned* S  = Rt + 256 * 128;         // 128 x 128 packed dwords

  const int t = threadIdx.x;
  const float step = expf(lstep[0]);
  const float alpha = 0.5f * step / (1.0f + step);
  const float c3 = 2.f / (1.f + step);

  // build T = alpha*(A+2I) into M, and T^T into Bt
#pragma unroll
  for (int i = 0; i < 64; ++i) {
    int idx = t + (i << 8);
    int r = idx >> 7, c = idx & 127;
    float d = (r == c) ? 1.f : 0.f;
    unsigned pk = packhl(alpha * (A[idx] + 2.f * d));
    Ml[r * SMD + c] = pk;
    Bt[c * SMD + r] = pk;
  }

  // Neumann: inv(I-T) ~ (I+T)(I+T2)(I+T4)(I+T8); U12=(I+T)(I+T2), U48=(I+T4)(I+T8)
  mm<0,0,0,0>(Ml, Bt, 0, 0, 0, 0, 0, 128, 128, 0.f);          // M = T2 (Bt=T^T)
  mm<0,0,1,2>(Ml, Bt, 0, 0, gU12t, 0, SMD, 128, 128, 0.f);    // gU12t = (T2*T+T2+T+I)^T
  transposeMB(Ml, Bt);                                        // Bt = T2^T
  mm<0,0,0,0>(Ml, Bt, 0, 0, 0, 0, 0, 128, 128, 0.f);          // M = T4
  transposeMB(Ml, Bt);                                        // Bt = T4^T
  mm<0,0,0,0>(Ml, Bt, 0, 0, 0, 0, 0, 128, 128, 0.f);          // M = T8
  mm<0,0,0,2>(Ml, Bt, 0, 0, 0, 0, 0, 128, 128, 0.f);          // M = U48 = T8*T4+T8+T4+I
  __syncthreads();                                            // drain Bt readers
  {
    const uint4* src = (const uint4*)gU12t;
    uint4* dst4 = (uint4*)Bt;
    for (int i = t; i < (128 * SMD) / 4; i += 256) dst4[i] = src[i];  // Bt = U12^T
  }
  mm<0,0,0,3>(Ml, Bt, 0, 0, 0, 0, 0, 128, 128, c3);           // M = ab = c3*U48*U12 - I

  if (blockIdx.x == 0) {
    // R path: Rt[0] = bb; dbl k uses A=pw(k)(M), B=R cols (global Rt rows)
    __syncthreads();
    if (t < 128) {
      float a2 = 0.f;
      for (int k = 0; k < 128; ++k) a2 = fmaf(unpackhl(Ml[t * SMD + k]), Bv[k], a2);
      Rt[t] = packhl(0.5f * step * (a2 + Bv[t]));
    }
    for (int k = 0; k < 8; ++k) {
      mm<0,1,1,0>(Ml, Bt, 0, Rt, Rt, 1 << k, 128, 128, 1 << k, 0.f);
      if (k < 7) {
        transposeMB(Ml, Bt);
        mm<0,0,0,0>(Ml, Bt, 0, 0, 0, 0, 0, 128, 128, 0.f);    // M = pw(k+1)
      }
    }
  } else {
    // S path: S[0] = C; 8 squarings to pw8; dbl k uses A=S rows, B=pw(8+k)(Bt)
    __syncthreads();
    if (t < 128) S[t] = packhl(Cv[t]);
    for (int k = 0; k < 8; ++k) {
      transposeMB(Ml, Bt);
      mm<0,0,0,0>(Ml, Bt, 0, 0, 0, 0, 0, 128, 128, 0.f);      // M = pw(k+1)
    }
    for (int k = 0; k < 7; ++k) {
      transposeMB(Ml, Bt);                                    // Bt = pw(8+k)^T
      mm<1,0,2,0>(Ml, Bt, S, 0, S, 1 << k, 0, 1 << k, 128, 0.f);
      if (k < 6)
        mm<0,0,0,0>(Ml, Bt, 0, 0, 0, 0, 0, 128, 128, 0.f);    // M = pw(9+k)
    }
  }
}

// ---------------------------------------------------------------------------
// K[t1*256 + t0] = S[t1] . Rt[t0]
// ---------------------------------------------------------------------------
__global__ __launch_bounds__(256) void kmat_k(const unsigned* __restrict__ Sdw,
                                              const unsigned* __restrict__ Rtdw,
                                              float* __restrict__ Kv) {
  __shared__ float srow[128];
  int t1 = blockIdx.x, t0 = threadIdx.x;
  if (t0 < 128) srow[t0] = unpackhl(Sdw[t1 * 128 + t0]);
  __syncthreads();
  const unsigned* rr = Rtdw + t0 * 128;
  float acc = 0.f;
#pragma unroll 8
  for (int k = 0; k < 128; k += 4) {
    uint4 q = *(const uint4*)(rr + k);
    acc = fmaf(srow[k],     unpackhl(q.x), acc);
    acc = fmaf(srow[k + 1], unpackhl(q.y), acc);
    acc = fmaf(srow[k + 2], unpackhl(q.z), acc);
    acc = fmaf(srow[k + 3], unpackhl(q.w), acc);
  }
  Kv[t1 * 256 + t0] = acc;
}

// ---------------------------------------------------------------------------
// Conv partials (proven rounds 2-3): task (m,c), c<=m, 528 blocks,
// XOR-swizzled LDS, register window shift, 4 outputs/thread.
// ---------------------------------------------------------------------------
__global__ __launch_bounds__(256) void conv_k(const float* __restrict__ u,
                                              const float* __restrict__ Kv,
                                              float* __restrict__ Pp) {
  __shared__ __align__(16) float ks[1024];
  __shared__ __align__(16) float usw[2048];

  int bid = blockIdx.x, tid = threadIdx.x;
  int m = 0;
  while ((m + 1) * (m + 2) / 2 <= bid) m++;
  int c = bid - m * (m + 1) / 2;
  int w0 = (m - c - 1) << 10;

  for (int idx = tid; idx < 1024; idx += 256) ks[idx] = Kv[(c << 10) + idx];
  for (int idx = tid; idx < 2048; idx += 256) {
    int gi = w0 + idx;
    float v = (gi >= 0) ? u[gi] : 0.f;
    int b = idx >> 2;
    int pb = b ^ ((b >> 3) & 7);
    usw[(pb << 2) | (idx & 3)] = v;
  }
  __syncthreads();

  int tb = tid << 2;

#define LD4(x)                                                      \
  (*(const float4*)&usw[((((x) >> 2) ^ ((((x) >> 2) >> 3) & 7)) << 2)])

  float4 wlo = LD4(1020 + tb);
  float4 whi = LD4(1024 + tb);
  float acc0 = 0.f, acc1 = 0.f, acc2 = 0.f, acc3 = 0.f;

#pragma unroll 4
  for (int s8 = 0; s8 < 1024; s8 += 4) {
    float4 k4 = *(const float4*)&ks[s8];
    acc0 = fmaf(k4.x, whi.x, acc0);
    acc0 = fmaf(k4.y, wlo.w, acc0);
    acc0 = fmaf(k4.z, wlo.z, acc0);
    acc0 = fmaf(k4.w, wlo.y, acc0);
    acc1 = fmaf(k4.x, whi.y, acc1);
    acc1 = fmaf(k4.y, whi.x, acc1);
    acc1 = fmaf(k4.z, wlo.w, acc1);
    acc1 = fmaf(k4.w, wlo.z, acc1);
    acc2 = fmaf(k4.x, whi.z, acc2);
    acc2 = fmaf(k4.y, whi.y, acc2);
    acc2 = fmaf(k4.z, whi.x, acc2);
    acc2 = fmaf(k4.w, wlo.w, acc2);
    acc3 = fmaf(k4.x, whi.w, acc3);
    acc3 = fmaf(k4.y, whi.z, acc3);
    acc3 = fmaf(k4.z, whi.y, acc3);
    acc3 = fmaf(k4.w, whi.x, acc3);
    if (s8 < 1020) {
      whi = wlo;
      wlo = LD4(1016 + tb - s8);
    }
  }
#undef LD4

  float* dst = Pp + (c << 15) + (m << 10) + tb;
  *(float4*)dst = make_float4(acc0, acc1, acc2, acc3);
}

// ---------------------------------------------------------------------------
// reduce: y[t] = D*u[t] + sum_{c<=t>>10} P[c][t]
// ---------------------------------------------------------------------------
__global__ __launch_bounds__(256) void reduce_k(const float* __restrict__ Pp,
                                                const float* __restrict__ u,
                                                const float* __restrict__ D,
                                                float* __restrict__ y) {
  int t = blockIdx.x * 256 + threadIdx.x;
  if (t >= L_SEQ) return;
  int mm_ = t >> 10;
  float acc = D[0] * u[t];
  for (int c = 0; c <= mm_; ++c) acc += Pp[(c << 15) + t];
  y[t] = acc;
}

// ---------------------------------------------------------------------------
// host side
// ws dword layout: gU12t 2x16896 [0,33792) | Rt [33792,66560) | S [66560,82944)
//                  Kv f32 [82944,115712) | Pp f32 [115712, +32*32768)
// ---------------------------------------------------------------------------
extern "C" void kernel_launch(void* const* d_in, const int* in_sizes, int n_in,
                              void* d_out, int out_size, void* d_ws, size_t ws_size,
                              hipStream_t stream) {
  (void)in_sizes; (void)n_in; (void)out_size; (void)ws_size;
  const float* u     = (const float*)d_in[0];
  const float* A     = (const float*)d_in[1];
  const float* B     = (const float*)d_in[2];
  const float* C     = (const float*)d_in[3];
  const float* D     = (const float*)d_in[4];
  const float* lstep = (const float*)d_in[5];
  float* y = (float*)d_out;
  unsigned* wsdw = (unsigned*)d_ws;
  float* wsf = (float*)d_ws;

  unsigned* Rt = wsdw + 33792;
  unsigned* S  = wsdw + 66560;
  float* Kv = wsf + 82944;
  float* Pp = wsf + 115712;

  (void)hipFuncSetAttribute((const void*)chain2,
                            hipFuncAttributeMaxDynamicSharedMemorySize, 135168);
  hipLaunchKernelGGL(chain2, dim3(2), dim3(256), 135168, stream, A, B, C, lstep, wsdw);
  hipLaunchKernelGGL(kmat_k, dim3(128), dim3(256), 0, stream, S, Rt, Kv);
  hipLaunchKernelGGL(conv_k, dim3(528), dim3(256), 0, stream, u, Kv, Pp);
  hipLaunchKernelGGL(reduce_k, dim3(128), dim3(256), 0, stream, Pp, u, D, y);
}

// Round 6
// 214.865 us; speedup vs baseline: 1.2068x; 1.2068x over previous
//
#include <hip/hip_runtime.h>
#include <math.h>

#define L_SEQ 32768
#define RSTR 136    // bf16 per LDS row (272 B = 17x16B; 4-bank lane spacing, <=2-way conflicts)
#define PL   17408  // u16 per LDS plane (128*136)
#define GP   16384  // u16 per global plane (stride 128)

typedef unsigned short u16;
typedef float f32x4 __attribute__((ext_vector_type(4)));
typedef short bf16x8 __attribute__((ext_vector_type(8)));
typedef u16 u16x4 __attribute__((ext_vector_type(4)));

__device__ __forceinline__ u16 f2bf(float x) {
  unsigned u = __float_as_uint(x);
  u = u + 0x7FFFu + ((u >> 16) & 1u);
  return (u16)(u >> 16);
}
__device__ __forceinline__ float bf2f(u16 h) {
  return __uint_as_float(((unsigned)h) << 16);
}
// sigma: k-dim storage permutation (involution). Element k lives at position
// sg(k); lane g's MFMA fragment (k = 32*kb + 8*g + i) is then CONTIGUOUS at
// position 32*g + 8*kb. Dot products are permutation-invariant.
__device__ __forceinline__ int sg(int k) {
  return (k & 7) + ((k >> 5) << 3) + (((k >> 3) & 3) << 5);
}
__device__ __forceinline__ f32x4 MF(bf16x8 a, bf16x8 b, f32x4 c) {
  return __builtin_amdgcn_mfma_f32_16x16x32_bf16(a, b, c, 0, 0, 0);
}

// ---------------------------------------------------------------------------
// One product step on a 1024-thread block: C = A(128x128) * B(128xN), M rows.
// fp32 emulated by 3 bf16 MFMAs (hh+hl+lh) on separate hi/lo planes.
// 16 waves, 32x32 tiles. acc = normal tile; accT = mfma(B,A) = transposed tile
// (gives contiguous runs for BOTH row-major and col-major outputs).
// ASRC: 0 = LDS M planes | 1 = global rows (gA, stride 128, planes +aPl)
// BSRC: 0 = LDS Bt planes | 1 = global transposed-layout rows (gB, +bPl)
// OUTM: 0 none | 2 write M (accT) AND Bt (acc) in-place
// OUTG: 0 none | 1 rows layout gO[(gOrow0+r)*128+sg(c)] (accT, mask r<Mrows)
//       2 transposed gO[(gOrow0+c)*128+sg(r)] (acc, mask c<N)
//       3 both layouts gO rows + gO2 transposed (U12 spill)
// MODE: 0 none | 2 +=E1(gT rows)+E2(T2: M/Bt)+I | 4 v=c3*(v+U12)-I (gE/gEt)
// ---------------------------------------------------------------------------
template<int ASRC,int BSRC,int OUTM,int OUTG,int MODE>
__device__ void mm(u16* lds, const u16* gA, int aPl, const u16* gB, int bPl,
                   u16* gO, int oPl, int gOrow0, u16* gO2,
                   int Mrows, int N, float c3, const u16* gE, const u16* gEt) {
  u16* Mh = lds;          u16* Ml = lds + PL;
  u16* Th = lds + 2 * PL; u16* Tl = lds + 3 * PL;
  const int t = threadIdx.x, lane = t & 63;
  const int la = lane & 15, g = lane >> 4;
  const int w = t >> 6;
  const int r0 = (w >> 2) << 5, c0 = (w & 3) << 5;
  constexpr bool doA = (OUTM == 2) || (OUTG == 2) || (OUTG == 3);
  constexpr bool doT = (OUTM >= 1) || (OUTG == 1) || (OUTG == 3);
  const bool act = (r0 < Mrows) && (c0 < N);

  __syncthreads();  // prior step's LDS writes visible

  f32x4 acc[2][2], accT[2][2];
#pragma unroll
  for (int i = 0; i < 2; ++i)
#pragma unroll
    for (int j = 0; j < 2; ++j) {
      acc[i][j] = (f32x4){0.f, 0.f, 0.f, 0.f};
      accT[i][j] = (f32x4){0.f, 0.f, 0.f, 0.f};
    }

  if (act) {
#pragma unroll
    for (int kb = 0; kb < 4; ++kb) {
      const int kp = (g << 5) + (kb << 3);
      bf16x8 Ah[2], Al[2], Bh[2], Bl[2];
#pragma unroll
      for (int fr = 0; fr < 2; ++fr) {
        const int ar = r0 + (fr << 4) + la;
        if constexpr (ASRC == 0) {
          Ah[fr] = *(const bf16x8*)(Mh + ar * RSTR + kp);
          Al[fr] = *(const bf16x8*)(Ml + ar * RSTR + kp);
        } else {
          Ah[fr] = *(const bf16x8*)(gA + ar * 128 + kp);
          Al[fr] = *(const bf16x8*)(gA + aPl + ar * 128 + kp);
        }
      }
#pragma unroll
      for (int fc = 0; fc < 2; ++fc) {
        const int bc = c0 + (fc << 4) + la;
        if constexpr (BSRC == 0) {
          Bh[fc] = *(const bf16x8*)(Th + bc * RSTR + kp);
          Bl[fc] = *(const bf16x8*)(Tl + bc * RSTR + kp);
        } else {
          Bh[fc] = *(const bf16x8*)(gB + bc * 128 + kp);
          Bl[fc] = *(const bf16x8*)(gB + bPl + bc * 128 + kp);
        }
      }
#pragma unroll
      for (int fr = 0; fr < 2; ++fr)
#pragma unroll
        for (int fc = 0; fc < 2; ++fc) {
          if constexpr (doA) {
            acc[fr][fc] = MF(Ah[fr], Bh[fc], acc[fr][fc]);
            acc[fr][fc] = MF(Ah[fr], Bl[fc], acc[fr][fc]);
            acc[fr][fc] = MF(Al[fr], Bh[fc], acc[fr][fc]);
          }
          if constexpr (doT) {
            accT[fr][fc] = MF(Bh[fc], Ah[fr], accT[fr][fc]);
            accT[fr][fc] = MF(Bh[fc], Al[fr], accT[fr][fc]);
            accT[fr][fc] = MF(Bl[fc], Ah[fr], accT[fr][fc]);
          }
        }
    }
  }

  __syncthreads();  // all operand reads drained -> in-place writes safe

  if (!act) return;

  if constexpr (doT) {
    // accT: lane holds C[rr][cb..cb+3] (row rr fixed, 4 consecutive cols)
#pragma unroll
    for (int fr = 0; fr < 2; ++fr)
#pragma unroll
      for (int fc = 0; fc < 2; ++fc) {
        const int rr = r0 + (fr << 4) + la;
        const int cb = c0 + (fc << 4) + (g << 2);
        const int scb = sg(cb);  // 4-aligned -> sg contiguous
        float v[4];
#pragma unroll
        for (int j = 0; j < 4; ++j) v[j] = accT[fr][fc][j];
        if constexpr (MODE == 2) {
#pragma unroll
          for (int j = 0; j < 4; ++j)
            v[j] += bf2f(gE[rr * 128 + scb + j]) + bf2f(gE[GP + rr * 128 + scb + j])  // T
                  + bf2f(Mh[rr * RSTR + scb + j]) + bf2f(Ml[rr * RSTR + scb + j])     // T2
                  + ((rr == cb + j) ? 1.f : 0.f);
        }
        if constexpr (MODE == 4) {
#pragma unroll
          for (int j = 0; j < 4; ++j)
            v[j] = c3 * (v[j] + bf2f(gE[rr * 128 + scb + j]) +
                         bf2f(gE[GP + rr * 128 + scb + j])) -
                   ((rr == cb + j) ? 1.f : 0.f);
        }
        u16x4 hi, lo;
#pragma unroll
        for (int j = 0; j < 4; ++j) {
          u16 h = f2bf(v[j]); hi[j] = h; lo[j] = f2bf(v[j] - bf2f(h));
        }
        if constexpr (OUTM == 2) {
          *(u16x4*)(Mh + rr * RSTR + scb) = hi;
          *(u16x4*)(Ml + rr * RSTR + scb) = lo;
        }
        if constexpr (OUTG == 1) {
          if (rr < Mrows) {
            *(u16x4*)(gO + (gOrow0 + rr) * 128 + scb) = hi;
            *(u16x4*)(gO + oPl + (gOrow0 + rr) * 128 + scb) = lo;
          }
        }
        if constexpr (OUTG == 3) {
          *(u16x4*)(gO + rr * 128 + scb) = hi;
          *(u16x4*)(gO + oPl + rr * 128 + scb) = lo;
        }
      }
  }
  if constexpr (doA) {
    // acc: lane holds C[rb..rb+3][cc] (col cc fixed, 4 consecutive rows)
#pragma unroll
    for (int fr = 0; fr < 2; ++fr)
#pragma unroll
      for (int fc = 0; fc < 2; ++fc) {
        const int cc = c0 + (fc << 4) + la;
        const int rb = r0 + (fr << 4) + (g << 2);
        const int srb = sg(rb);
        float v[4];
#pragma unroll
        for (int j = 0; j < 4; ++j) v[j] = acc[fr][fc][j];
        if constexpr (MODE == 2) {
          const int scc = sg(cc);
#pragma unroll
          for (int j = 0; j < 4; ++j)
            v[j] += bf2f(gE[(rb + j) * 128 + scc]) + bf2f(gE[GP + (rb + j) * 128 + scc]) // T
                  + bf2f(Th[cc * RSTR + srb + j]) + bf2f(Tl[cc * RSTR + srb + j])        // T2
                  + ((rb + j == cc) ? 1.f : 0.f);
        }
        if constexpr (MODE == 4) {
#pragma unroll
          for (int j = 0; j < 4; ++j)
            v[j] = c3 * (v[j] + bf2f(gEt[cc * 128 + srb + j]) +
                         bf2f(gEt[GP + cc * 128 + srb + j])) -
                   ((rb + j == cc) ? 1.f : 0.f);
        }
        u16x4 hi, lo;
#pragma unroll
        for (int j = 0; j < 4; ++j) {
          u16 h = f2bf(v[j]); hi[j] = h; lo[j] = f2bf(v[j] - bf2f(h));
        }
        if constexpr (OUTM == 2) {
          *(u16x4*)(Th + cc * RSTR + srb) = hi;
          *(u16x4*)(Tl + cc * RSTR + srb) = lo;
        }
        if constexpr (OUTG == 2) {
          if (cc < N) {
            *(u16x4*)(gO + (gOrow0 + cc) * 128 + srb) = hi;
            *(u16x4*)(gO + oPl + (gOrow0 + cc) * 128 + srb) = lo;
          }
        }
        if constexpr (OUTG == 3) {
          *(u16x4*)(gO2 + cc * 128 + srb) = hi;
          *(u16x4*)(gO2 + oPl + cc * 128 + srb) = lo;
        }
      }
  }
}

// ---------------------------------------------------------------------------
// Chain: 2 independent 1024-thread blocks (16 waves = 4/SIMD).
// Neumann (4 products): T2 -> U12(spill) -> T4 -> ab = c3*(U12*T4+U12)-I
//   [inv(I-T) ~ (I+T)(I+T2)(I+T4); ||T||^8 ~ 6e-9 truncation]
// block 0: R-cols doubling (rt = R^T, 256x128 global planes), 8 dbl + 7 sq
// block 1: S-rows doubling (gs, 128x128 global planes), 14 sq + 7 dbl
// ---------------------------------------------------------------------------
__global__ void __launch_bounds__(1024) chain_k(const float* __restrict__ A,
                                                const float* __restrict__ Bv,
                                                const float* __restrict__ Cv,
                                                const float* __restrict__ lstep,
                                                u16* ws) {
  extern __shared__ u16 lds[];
  const int bid = blockIdx.x;
  u16* gT    = ws + bid * 131072;  // per-block spills: T rows (2 planes)
  u16* gU12  = gT + 32768;         // U12 rows
  u16* gU12t = gT + 65536;         // U12 transposed
  u16* rt = ws + 262144;           // R^T: 256 rows x 128, 2 planes (+32768)
  u16* gs = ws + 327680;           // S rows: 128 x 128, 2 planes (+GP)

  const int t = threadIdx.x;
  const float step = expf(lstep[0]);
  const float alpha = 0.5f * step / (1.f + step);
  const float c3 = 2.f / (1.f + step);
  u16* Mh = lds; u16* Ml = lds + PL; u16* Th = lds + 2 * PL; u16* Tl = lds + 3 * PL;

  // s0: T = alpha*(A+2I) -> LDS M rows, LDS Bt cols, global gT rows
#pragma unroll
  for (int i = 0; i < 4; ++i) {
    int e4 = (t + (i << 10)) << 2;
    int r = e4 >> 7, c = e4 & 127;
    float4 av = *(const float4*)(A + e4);
    float vv[4] = {av.x, av.y, av.z, av.w};
    u16x4 hi, lo;
#pragma unroll
    for (int j = 0; j < 4; ++j) {
      float v = alpha * (vv[j] + ((r == c + j) ? 2.f : 0.f));
      u16 h = f2bf(v); hi[j] = h; lo[j] = f2bf(v - bf2f(h));
    }
    int sc = sg(c), sr = sg(r);
    *(u16x4*)(Mh + r * RSTR + sc) = hi;
    *(u16x4*)(Ml + r * RSTR + sc) = lo;
    *(u16x4*)(gT + r * 128 + sc) = hi;
    *(u16x4*)(gT + GP + r * 128 + sc) = lo;
#pragma unroll
    for (int j = 0; j < 4; ++j) {
      Th[(c + j) * RSTR + sr] = hi[j];
      Tl[(c + j) * RSTR + sr] = lo[j];
    }
  }

  // Neumann
  mm<0,0,2,0,0>(lds, 0,0, 0,0, 0,0,0,0, 128,128, 0.f, 0,0);                   // M,Bt = T2
  mm<1,0,0,3,2>(lds, gT,GP, 0,0, gU12,GP,0,gU12t, 128,128, 0.f, gT,0);        // U12 spill
  mm<0,0,2,0,0>(lds, 0,0, 0,0, 0,0,0,0, 128,128, 0.f, 0,0);                   // M,Bt = T4
  mm<1,0,2,0,4>(lds, gU12,GP, 0,0, 0,0,0,0, 128,128, c3, gU12,gU12t);         // M,Bt = ab

  if (bid == 0) {
    __syncthreads();
    if (t < 128) {  // bb = (step/2)*(ab*B + B) -> rt row 0
      float a2 = 0.f;
      for (int p = 0; p < 128; ++p)
        a2 = fmaf(bf2f(Mh[t * RSTR + p]) + bf2f(Ml[t * RSTR + p]), Bv[sg(p)], a2);
      float v = 0.5f * step * (a2 + Bv[t]);
      u16 h = f2bf(v);
      rt[sg(t)] = h;
      rt[32768 + sg(t)] = f2bf(v - bf2f(h));
    }
    for (int k = 0; k < 8; ++k) {
      mm<0,1,0,2,0>(lds, 0,0, rt,32768, rt,32768,(1<<k),0, 128,(1<<k), 0.f, 0,0);
      if (k < 7) mm<0,0,2,0,0>(lds, 0,0, 0,0, 0,0,0,0, 128,128, 0.f, 0,0);
    }
  } else {
    __syncthreads();
    if (t < 128) {  // S row 0 = C
      float v = Cv[t];
      u16 h = f2bf(v);
      gs[sg(t)] = h;
      gs[GP + sg(t)] = f2bf(v - bf2f(h));
    }
    for (int k = 0; k < 8; ++k)
      mm<0,0,2,0,0>(lds, 0,0, 0,0, 0,0,0,0, 128,128, 0.f, 0,0);               // -> pw8
    for (int k = 0; k < 7; ++k) {
      mm<1,0,0,1,0>(lds, gs,GP, 0,0, gs,GP,(1<<k),0, (1<<k),128, 0.f, 0,0);
      if (k < 6) mm<0,0,2,0,0>(lds, 0,0, 0,0, 0,0,0,0, 128,128, 0.f, 0,0);
    }
  }
}

// ---------------------------------------------------------------------------
// K[t1*256 + t0] = S[t1] . R[:,t0]  (both rows sigma-ordered identically)
// ---------------------------------------------------------------------------
__global__ __launch_bounds__(256) void kmat_k(const u16* __restrict__ gs,
                                              const u16* __restrict__ rt,
                                              float* __restrict__ Kv) {
  __shared__ float srow[128];
  int t1 = blockIdx.x, t0 = threadIdx.x;
  if (t0 < 128)
    srow[t0] = bf2f(gs[t1 * 128 + t0]) + bf2f(gs[GP + t1 * 128 + t0]);
  __syncthreads();
  const u16* rh = rt + t0 * 128;
  const u16* rl = rt + 32768 + t0 * 128;
  float acc = 0.f;
#pragma unroll 4
  for (int p = 0; p < 128; p += 8) {
    uint4 qh = *(const uint4*)(rh + p);
    uint4 ql = *(const uint4*)(rl + p);
    unsigned dh[4] = {qh.x, qh.y, qh.z, qh.w};
    unsigned dl[4] = {ql.x, ql.y, ql.z, ql.w};
#pragma unroll
    for (int j = 0; j < 4; ++j) {
      acc = fmaf(srow[p + 2 * j],     bf2f((u16)dh[j]) + bf2f((u16)dl[j]), acc);
      acc = fmaf(srow[p + 2 * j + 1],
                 bf2f((u16)(dh[j] >> 16)) + bf2f((u16)(dl[j] >> 16)), acc);
    }
  }
  Kv[t1 * 256 + t0] = acc;
}

// ---------------------------------------------------------------------------
// Conv partials (proven rounds 2/3/5): task (m,c), c<=m, 528 blocks,
// XOR-swizzled LDS, register window shift, 4 outputs/thread.
// ---------------------------------------------------------------------------
__global__ __launch_bounds__(256) void conv_k(const float* __restrict__ u,
                                              const float* __restrict__ Kv,
                                              float* __restrict__ Pp) {
  __shared__ __align__(16) float ks[1024];
  __shared__ __align__(16) float usw[2048];

  int bid = blockIdx.x, tid = threadIdx.x;
  int m = 0;
  while ((m + 1) * (m + 2) / 2 <= bid) m++;
  int c = bid - m * (m + 1) / 2;
  int w0 = (m - c - 1) << 10;

  for (int idx = tid; idx < 1024; idx += 256) ks[idx] = Kv[(c << 10) + idx];
  for (int idx = tid; idx < 2048; idx += 256) {
    int gi = w0 + idx;
    float v = (gi >= 0) ? u[gi] : 0.f;
    int b = idx >> 2;
    int pb = b ^ ((b >> 3) & 7);
    usw[(pb << 2) | (idx & 3)] = v;
  }
  __syncthreads();

  int tb = tid << 2;

#define LD4(x)                                                      \
  (*(const float4*)&usw[((((x) >> 2) ^ ((((x) >> 2) >> 3) & 7)) << 2)])

  float4 wlo = LD4(1020 + tb);
  float4 whi = LD4(1024 + tb);
  float acc0 = 0.f, acc1 = 0.f, acc2 = 0.f, acc3 = 0.f;

#pragma unroll 4
  for (int s8 = 0; s8 < 1024; s8 += 4) {
    float4 k4 = *(const float4*)&ks[s8];
    acc0 = fmaf(k4.x, whi.x, acc0);
    acc0 = fmaf(k4.y, wlo.w, acc0);
    acc0 = fmaf(k4.z, wlo.z, acc0);
    acc0 = fmaf(k4.w, wlo.y, acc0);
    acc1 = fmaf(k4.x, whi.y, acc1);
    acc1 = fmaf(k4.y, whi.x, acc1);
    acc1 = fmaf(k4.z, wlo.w, acc1);
    acc1 = fmaf(k4.w, wlo.z, acc1);
    acc2 = fmaf(k4.x, whi.z, acc2);
    acc2 = fmaf(k4.y, whi.y, acc2);
    acc2 = fmaf(k4.z, whi.x, acc2);
    acc2 = fmaf(k4.w, wlo.w, acc2);
    acc3 = fmaf(k4.x, whi.w, acc3);
    acc3 = fmaf(k4.y, whi.z, acc3);
    acc3 = fmaf(k4.z, whi.y, acc3);
    acc3 = fmaf(k4.w, whi.x, acc3);
    if (s8 < 1020) {
      whi = wlo;
      wlo = LD4(1016 + tb - s8);
    }
  }
#undef LD4

  float* dst = Pp + (c << 15) + (m << 10) + tb;
  *(float4*)dst = make_float4(acc0, acc1, acc2, acc3);
}

// ---------------------------------------------------------------------------
// reduce: y[t] = D*u[t] + sum_{c<=t>>10} P[c][t]
// ---------------------------------------------------------------------------
__global__ __launch_bounds__(256) void reduce_k(const float* __restrict__ Pp,
                                                const float* __restrict__ u,
                                                const float* __restrict__ D,
                                                float* __restrict__ y) {
  int t = blockIdx.x * 256 + threadIdx.x;
  if (t >= L_SEQ) return;
  int mm_ = t >> 10;
  float acc = D[0] * u[t];
  for (int c = 0; c <= mm_; ++c) acc += Pp[(c << 15) + t];
  y[t] = acc;
}

// ---------------------------------------------------------------------------
// host side. ws u16 layout:
//   [0, 262144)      per-block Neumann spills (2 x 131072)
//   [262144, 327680) rt (R^T) 2 planes of 32768
//   [327680, 360448) gs (S)   2 planes of 16384
//   byte 720896: Kv f32[32768]; then Pp f32[32*32768]
// ---------------------------------------------------------------------------
extern "C" void kernel_launch(void* const* d_in, const int* in_sizes, int n_in,
                              void* d_out, int out_size, void* d_ws, size_t ws_size,
                              hipStream_t stream) {
  (void)in_sizes; (void)n_in; (void)out_size; (void)ws_size;
  const float* u     = (const float*)d_in[0];
  const float* A     = (const float*)d_in[1];
  const float* B     = (const float*)d_in[2];
  const float* C     = (const float*)d_in[3];
  const float* D     = (const float*)d_in[4];
  const float* lstep = (const float*)d_in[5];
  float* y = (float*)d_out;
  u16* ws = (u16*)d_ws;

  u16* rt = ws + 262144;
  u16* gs = ws + 327680;
  float* Kv = (float*)((char*)d_ws + 720896);
  float* Pp = Kv + 32768;

  (void)hipFuncSetAttribute((const void*)chain_k,
                            hipFuncAttributeMaxDynamicSharedMemorySize, 139264);
  hipLaunchKernelGGL(chain_k, dim3(2), dim3(1024), 139264, stream, A, B, C, lstep, ws);
  hipLaunchKernelGGL(kmat_k, dim3(128), dim3(256), 0, stream, gs, rt, Kv);
  hipLaunchKernelGGL(conv_k, dim3(528), dim3(256), 0, stream, u, Kv, Pp);
  hipLaunchKernelGGL(reduce_k, dim3(128), dim3(256), 0, stream, Pp, u, D, y);
}

// Round 7
// 210.230 us; speedup vs baseline: 1.2335x; 1.0220x over previous
//
#include <hip/hip_runtime.h>
#include <math.h>

#define L_SEQ 32768
#define RSTR 136    // bf16 per LDS row (272 B = 17x16B; 4-bank lane spacing, <=2-way conflicts)
#define PL   17408  // u16 per LDS plane (128*136)
#define GP   16384  // u16 per global plane (stride 128)

typedef unsigned short u16;
typedef float f32x4 __attribute__((ext_vector_type(4)));
typedef short bf16x8 __attribute__((ext_vector_type(8)));
typedef u16 u16x4 __attribute__((ext_vector_type(4)));

__device__ __forceinline__ u16 f2bf(float x) {
  unsigned u = __float_as_uint(x);
  u = u + 0x7FFFu + ((u >> 16) & 1u);
  return (u16)(u >> 16);
}
__device__ __forceinline__ float bf2f(u16 h) {
  return __uint_as_float(((unsigned)h) << 16);
}
// sigma: k-dim storage permutation (involution). Element k lives at position
// sg(k); lane g's MFMA fragment (k = 32*kb + 8*g + i) is then CONTIGUOUS at
// position 32*g + 8*kb. Dot products are permutation-invariant.
__device__ __forceinline__ int sg(int k) {
  return (k & 7) + ((k >> 5) << 3) + (((k >> 3) & 3) << 5);
}
__device__ __forceinline__ f32x4 MF(bf16x8 a, bf16x8 b, f32x4 c) {
  return __builtin_amdgcn_mfma_f32_16x16x32_bf16(a, b, c, 0, 0, 0);
}

// ---------------------------------------------------------------------------
// One product step on a 1024-thread block: C = A(128x128) * B(128xN), M rows.
// fp32 emulated by 3 bf16 MFMAs (hh+hl+lh) on separate hi/lo planes.
// 16 waves, 32x32 tiles. acc = normal tile; accT = mfma(B,A) = transposed tile
// (gives contiguous runs for BOTH row-major and col-major outputs).
// ASRC: 0 = LDS M planes | 1 = global rows (gA, stride 128, planes +aPl)
// BSRC: 0 = LDS Bt planes | 1 = global transposed-layout rows (gB, +bPl)
// OUTM: 0 none | 2 write M (accT) AND Bt (acc) in-place
// OUTG: 0 none | 1 rows layout gO[(gOrow0+r)*128+sg(c)] (accT, mask r<Mrows)
//       2 transposed gO[(gOrow0+c)*128+sg(r)] (acc, mask c<N)
//       3 both layouts gO rows + gO2 transposed (U12 spill)
// MODE: 0 none | 2 +=E1(gT rows)+E2(T2: M/Bt)+I | 4 v=c3*(v+U12)-I (gE/gEt)
// ---------------------------------------------------------------------------
template<int ASRC,int BSRC,int OUTM,int OUTG,int MODE>
__device__ void mm(u16* lds, const u16* gA, int aPl, const u16* gB, int bPl,
                   u16* gO, int oPl, int gOrow0, u16* gO2,
                   int Mrows, int N, float c3, const u16* gE, const u16* gEt) {
  u16* Mh = lds;          u16* Ml = lds + PL;
  u16* Th = lds + 2 * PL; u16* Tl = lds + 3 * PL;
  const int t = threadIdx.x, lane = t & 63;
  const int la = lane & 15, g = lane >> 4;
  const int w = t >> 6;
  const int r0 = (w >> 2) << 5, c0 = (w & 3) << 5;
  constexpr bool doA = (OUTM == 2) || (OUTG == 2) || (OUTG == 3);
  constexpr bool doT = (OUTM >= 1) || (OUTG == 1) || (OUTG == 3);
  const bool act = (r0 < Mrows) && (c0 < N);

  __syncthreads();  // prior step's LDS writes visible

  f32x4 acc[2][2], accT[2][2];
#pragma unroll
  for (int i = 0; i < 2; ++i)
#pragma unroll
    for (int j = 0; j < 2; ++j) {
      acc[i][j] = (f32x4){0.f, 0.f, 0.f, 0.f};
      accT[i][j] = (f32x4){0.f, 0.f, 0.f, 0.f};
    }

  if (act) {
#pragma unroll
    for (int kb = 0; kb < 4; ++kb) {
      const int kp = (g << 5) + (kb << 3);
      bf16x8 Ah[2], Al[2], Bh[2], Bl[2];
#pragma unroll
      for (int fr = 0; fr < 2; ++fr) {
        const int ar = r0 + (fr << 4) + la;
        if constexpr (ASRC == 0) {
          Ah[fr] = *(const bf16x8*)(Mh + ar * RSTR + kp);
          Al[fr] = *(const bf16x8*)(Ml + ar * RSTR + kp);
        } else {
          Ah[fr] = *(const bf16x8*)(gA + ar * 128 + kp);
          Al[fr] = *(const bf16x8*)(gA + aPl + ar * 128 + kp);
        }
      }
#pragma unroll
      for (int fc = 0; fc < 2; ++fc) {
        const int bc = c0 + (fc << 4) + la;
        if constexpr (BSRC == 0) {
          Bh[fc] = *(const bf16x8*)(Th + bc * RSTR + kp);
          Bl[fc] = *(const bf16x8*)(Tl + bc * RSTR + kp);
        } else {
          Bh[fc] = *(const bf16x8*)(gB + bc * 128 + kp);
          Bl[fc] = *(const bf16x8*)(gB + bPl + bc * 128 + kp);
        }
      }
#pragma unroll
      for (int fr = 0; fr < 2; ++fr)
#pragma unroll
        for (int fc = 0; fc < 2; ++fc) {
          if constexpr (doA) {
            acc[fr][fc] = MF(Ah[fr], Bh[fc], acc[fr][fc]);
            acc[fr][fc] = MF(Ah[fr], Bl[fc], acc[fr][fc]);
            acc[fr][fc] = MF(Al[fr], Bh[fc], acc[fr][fc]);
          }
          if constexpr (doT) {
            accT[fr][fc] = MF(Bh[fc], Ah[fr], accT[fr][fc]);
            accT[fr][fc] = MF(Bh[fc], Al[fr], accT[fr][fc]);
            accT[fr][fc] = MF(Bl[fc], Ah[fr], accT[fr][fc]);
          }
        }
    }
  }

  __syncthreads();  // all operand reads drained -> in-place writes safe

  if (!act) return;

  if constexpr (doT) {
    // accT: lane holds C[rr][cb..cb+3] (row rr fixed, 4 consecutive cols)
#pragma unroll
    for (int fr = 0; fr < 2; ++fr)
#pragma unroll
      for (int fc = 0; fc < 2; ++fc) {
        const int rr = r0 + (fr << 4) + la;
        const int cb = c0 + (fc << 4) + (g << 2);
        const int scb = sg(cb);  // 4-aligned -> sg contiguous
        float v[4];
#pragma unroll
        for (int j = 0; j < 4; ++j) v[j] = accT[fr][fc][j];
        if constexpr (MODE == 2) {
#pragma unroll
          for (int j = 0; j < 4; ++j)
            v[j] += bf2f(gE[rr * 128 + scb + j]) + bf2f(gE[GP + rr * 128 + scb + j])  // T
                  + bf2f(Mh[rr * RSTR + scb + j]) + bf2f(Ml[rr * RSTR + scb + j])     // T2
                  + ((rr == cb + j) ? 1.f : 0.f);
        }
        if constexpr (MODE == 4) {
#pragma unroll
          for (int j = 0; j < 4; ++j)
            v[j] = c3 * (v[j] + bf2f(gE[rr * 128 + scb + j]) +
                         bf2f(gE[GP + rr * 128 + scb + j])) -
                   ((rr == cb + j) ? 1.f : 0.f);
        }
        u16x4 hi, lo;
#pragma unroll
        for (int j = 0; j < 4; ++j) {
          u16 h = f2bf(v[j]); hi[j] = h; lo[j] = f2bf(v[j] - bf2f(h));
        }
        if constexpr (OUTM == 2) {
          *(u16x4*)(Mh + rr * RSTR + scb) = hi;
          *(u16x4*)(Ml + rr * RSTR + scb) = lo;
        }
        if constexpr (OUTG == 1) {
          if (rr < Mrows) {
            *(u16x4*)(gO + (gOrow0 + rr) * 128 + scb) = hi;
            *(u16x4*)(gO + oPl + (gOrow0 + rr) * 128 + scb) = lo;
          }
        }
        if constexpr (OUTG == 3) {
          *(u16x4*)(gO + rr * 128 + scb) = hi;
          *(u16x4*)(gO + oPl + rr * 128 + scb) = lo;
        }
      }
  }
  if constexpr (doA) {
    // acc: lane holds C[rb..rb+3][cc] (col cc fixed, 4 consecutive rows)
#pragma unroll
    for (int fr = 0; fr < 2; ++fr)
#pragma unroll
      for (int fc = 0; fc < 2; ++fc) {
        const int cc = c0 + (fc << 4) + la;
        const int rb = r0 + (fr << 4) + (g << 2);
        const int srb = sg(rb);
        float v[4];
#pragma unroll
        for (int j = 0; j < 4; ++j) v[j] = acc[fr][fc][j];
        if constexpr (MODE == 2) {
          const int scc = sg(cc);
#pragma unroll
          for (int j = 0; j < 4; ++j)
            v[j] += bf2f(gE[(rb + j) * 128 + scc]) + bf2f(gE[GP + (rb + j) * 128 + scc]) // T
                  + bf2f(Th[cc * RSTR + srb + j]) + bf2f(Tl[cc * RSTR + srb + j])        // T2
                  + ((rb + j == cc) ? 1.f : 0.f);
        }
        if constexpr (MODE == 4) {
#pragma unroll
          for (int j = 0; j < 4; ++j)
            v[j] = c3 * (v[j] + bf2f(gEt[cc * 128 + srb + j]) +
                         bf2f(gEt[GP + cc * 128 + srb + j])) -
                   ((rb + j == cc) ? 1.f : 0.f);
        }
        u16x4 hi, lo;
#pragma unroll
        for (int j = 0; j < 4; ++j) {
          u16 h = f2bf(v[j]); hi[j] = h; lo[j] = f2bf(v[j] - bf2f(h));
        }
        if constexpr (OUTM == 2) {
          *(u16x4*)(Th + cc * RSTR + srb) = hi;
          *(u16x4*)(Tl + cc * RSTR + srb) = lo;
        }
        if constexpr (OUTG == 2) {
          if (cc < N) {
            *(u16x4*)(gO + (gOrow0 + cc) * 128 + srb) = hi;
            *(u16x4*)(gO + oPl + (gOrow0 + cc) * 128 + srb) = lo;
          }
        }
        if constexpr (OUTG == 3) {
          *(u16x4*)(gO2 + cc * 128 + srb) = hi;
          *(u16x4*)(gO2 + oPl + cc * 128 + srb) = lo;
        }
      }
  }
}

// ---------------------------------------------------------------------------
// Chain: 2 independent 1024-thread blocks (16 waves = 4/SIMD).
// __launch_bounds__(1024, 4): 4 waves/EU is the true minimum for a
// 1024-thread single-resident block -> VGPR budget 128 (was 64 -> acc spills).
// Neumann (4 products): T2 -> U12(spill) -> T4 -> ab = c3*(U12*T4+U12)-I
// block 0: R-cols doubling (rt = R^T, 256x128 global planes), 8 dbl + 7 sq
// block 1: S-rows doubling (gs, 128x128 global planes), 14 sq + 7 dbl
// ---------------------------------------------------------------------------
__global__ void __launch_bounds__(1024, 4) chain_k(const float* __restrict__ A,
                                                   const float* __restrict__ Bv,
                                                   const float* __restrict__ Cv,
                                                   const float* __restrict__ lstep,
                                                   u16* ws) {
  extern __shared__ u16 lds[];
  const int bid = blockIdx.x;
  u16* gT    = ws + bid * 131072;  // per-block spills: T rows (2 planes)
  u16* gU12  = gT + 32768;         // U12 rows
  u16* gU12t = gT + 65536;         // U12 transposed
  u16* rt = ws + 262144;           // R^T: 256 rows x 128, 2 planes (+32768)
  u16* gs = ws + 327680;           // S rows: 128 x 128, 2 planes (+GP)

  const int t = threadIdx.x;
  const float step = expf(lstep[0]);
  const float alpha = 0.5f * step / (1.f + step);
  const float c3 = 2.f / (1.f + step);
  u16* Mh = lds; u16* Ml = lds + PL; u16* Th = lds + 2 * PL; u16* Tl = lds + 3 * PL;

  // s0: T = alpha*(A+2I) -> LDS M rows, LDS Bt cols, global gT rows
#pragma unroll
  for (int i = 0; i < 4; ++i) {
    int e4 = (t + (i << 10)) << 2;
    int r = e4 >> 7, c = e4 & 127;
    float4 av = *(const float4*)(A + e4);
    float vv[4] = {av.x, av.y, av.z, av.w};
    u16x4 hi, lo;
#pragma unroll
    for (int j = 0; j < 4; ++j) {
      float v = alpha * (vv[j] + ((r == c + j) ? 2.f : 0.f));
      u16 h = f2bf(v); hi[j] = h; lo[j] = f2bf(v - bf2f(h));
    }
    int sc = sg(c), sr = sg(r);
    *(u16x4*)(Mh + r * RSTR + sc) = hi;
    *(u16x4*)(Ml + r * RSTR + sc) = lo;
    *(u16x4*)(gT + r * 128 + sc) = hi;
    *(u16x4*)(gT + GP + r * 128 + sc) = lo;
#pragma unroll
    for (int j = 0; j < 4; ++j) {
      Th[(c + j) * RSTR + sr] = hi[j];
      Tl[(c + j) * RSTR + sr] = lo[j];
    }
  }

  // Neumann
  mm<0,0,2,0,0>(lds, 0,0, 0,0, 0,0,0,0, 128,128, 0.f, 0,0);                   // M,Bt = T2
  mm<1,0,0,3,2>(lds, gT,GP, 0,0, gU12,GP,0,gU12t, 128,128, 0.f, gT,0);        // U12 spill
  mm<0,0,2,0,0>(lds, 0,0, 0,0, 0,0,0,0, 128,128, 0.f, 0,0);                   // M,Bt = T4
  mm<1,0,2,0,4>(lds, gU12,GP, 0,0, 0,0,0,0, 128,128, c3, gU12,gU12t);         // M,Bt = ab

  if (bid == 0) {
    __syncthreads();
    if (t < 128) {  // bb = (step/2)*(ab*B + B) -> rt row 0
      float a2 = 0.f;
      for (int p = 0; p < 128; ++p)
        a2 = fmaf(bf2f(Mh[t * RSTR + p]) + bf2f(Ml[t * RSTR + p]), Bv[sg(p)], a2);
      float v = 0.5f * step * (a2 + Bv[t]);
      u16 h = f2bf(v);
      rt[sg(t)] = h;
      rt[32768 + sg(t)] = f2bf(v - bf2f(h));
    }
    for (int k = 0; k < 8; ++k) {
      mm<0,1,0,2,0>(lds, 0,0, rt,32768, rt,32768,(1<<k),0, 128,(1<<k), 0.f, 0,0);
      if (k < 7) mm<0,0,2,0,0>(lds, 0,0, 0,0, 0,0,0,0, 128,128, 0.f, 0,0);
    }
  } else {
    __syncthreads();
    if (t < 128) {  // S row 0 = C
      float v = Cv[t];
      u16 h = f2bf(v);
      gs[sg(t)] = h;
      gs[GP + sg(t)] = f2bf(v - bf2f(h));
    }
    for (int k = 0; k < 8; ++k)
      mm<0,0,2,0,0>(lds, 0,0, 0,0, 0,0,0,0, 128,128, 0.f, 0,0);               // -> pw8
    for (int k = 0; k < 7; ++k) {
      mm<1,0,0,1,0>(lds, gs,GP, 0,0, gs,GP,(1<<k),0, (1<<k),128, 0.f, 0,0);
      if (k < 6) mm<0,0,2,0,0>(lds, 0,0, 0,0, 0,0,0,0, 128,128, 0.f, 0,0);
    }
  }
}

// ---------------------------------------------------------------------------
// K[t1*256 + t0] = S[t1] . R[:,t0]  (both rows sigma-ordered identically)
// ---------------------------------------------------------------------------
__global__ __launch_bounds__(256) void kmat_k(const u16* __restrict__ gs,
                                              const u16* __restrict__ rt,
                                              float* __restrict__ Kv) {
  __shared__ float srow[128];
  int t1 = blockIdx.x, t0 = threadIdx.x;
  if (t0 < 128)
    srow[t0] = bf2f(gs[t1 * 128 + t0]) + bf2f(gs[GP + t1 * 128 + t0]);
  __syncthreads();
  const u16* rh = rt + t0 * 128;
  const u16* rl = rt + 32768 + t0 * 128;
  float acc = 0.f;
#pragma unroll 4
  for (int p = 0; p < 128; p += 8) {
    uint4 qh = *(const uint4*)(rh + p);
    uint4 ql = *(const uint4*)(rl + p);
    unsigned dh[4] = {qh.x, qh.y, qh.z, qh.w};
    unsigned dl[4] = {ql.x, ql.y, ql.z, ql.w};
#pragma unroll
    for (int j = 0; j < 4; ++j) {
      acc = fmaf(srow[p + 2 * j],     bf2f((u16)dh[j]) + bf2f((u16)dl[j]), acc);
      acc = fmaf(srow[p + 2 * j + 1],
                 bf2f((u16)(dh[j] >> 16)) + bf2f((u16)(dl[j] >> 16)), acc);
    }
  }
  Kv[t1 * 256 + t0] = acc;
}

// ---------------------------------------------------------------------------
// Conv partials. TS=512: task (m,c), c<=m, m<64 -> 2080 blocks (~8/CU for
// latency hiding). 128 thr x 4 outputs. XOR-swizzled LDS, register window
// shift (proven inner loop). Output packed by task id: Pp[bid*512 + i].
// ---------------------------------------------------------------------------
__global__ __launch_bounds__(128) void conv_k(const float* __restrict__ u,
                                              const float* __restrict__ Kv,
                                              float* __restrict__ Pp) {
  __shared__ __align__(16) float ks[512];
  __shared__ __align__(16) float usw[1024];

  int bid = blockIdx.x, tid = threadIdx.x;
  int m = (int)((sqrtf(8.f * (float)bid + 1.f) - 1.f) * 0.5f);
  while ((m + 1) * (m + 2) / 2 <= bid) ++m;
  while (m * (m + 1) / 2 > bid) --m;
  int c = bid - m * (m + 1) / 2;
  int w0 = (m - c - 1) << 9;   // logical us[li] = u[w0 + li]

  for (int idx = tid; idx < 512; idx += 128) ks[idx] = Kv[(c << 9) + idx];
  for (int idx = tid; idx < 1024; idx += 128) {
    int gi = w0 + idx;
    float v = (gi >= 0) ? u[gi] : 0.f;
    int b = idx >> 2;
    int pb = b ^ ((b >> 3) & 7);
    usw[(pb << 2) | (idx & 3)] = v;
  }
  __syncthreads();

  int tb = tid << 2;

#define LD4(x)                                                      \
  (*(const float4*)&usw[((((x) >> 2) ^ ((((x) >> 2) >> 3) & 7)) << 2)])

  float4 wlo = LD4(508 + tb);
  float4 whi = LD4(512 + tb);
  float acc0 = 0.f, acc1 = 0.f, acc2 = 0.f, acc3 = 0.f;

#pragma unroll 4
  for (int s8 = 0; s8 < 512; s8 += 4) {
    float4 k4 = *(const float4*)&ks[s8];
    acc0 = fmaf(k4.x, whi.x, acc0);
    acc0 = fmaf(k4.y, wlo.w, acc0);
    acc0 = fmaf(k4.z, wlo.z, acc0);
    acc0 = fmaf(k4.w, wlo.y, acc0);
    acc1 = fmaf(k4.x, whi.y, acc1);
    acc1 = fmaf(k4.y, whi.x, acc1);
    acc1 = fmaf(k4.z, wlo.w, acc1);
    acc1 = fmaf(k4.w, wlo.z, acc1);
    acc2 = fmaf(k4.x, whi.z, acc2);
    acc2 = fmaf(k4.y, whi.y, acc2);
    acc2 = fmaf(k4.z, whi.x, acc2);
    acc2 = fmaf(k4.w, wlo.w, acc2);
    acc3 = fmaf(k4.x, whi.w, acc3);
    acc3 = fmaf(k4.y, whi.z, acc3);
    acc3 = fmaf(k4.z, whi.y, acc3);
    acc3 = fmaf(k4.w, whi.x, acc3);
    if (s8 < 508) {
      whi = wlo;
      wlo = LD4(504 + tb - s8);
    }
  }
#undef LD4

  float* dst = Pp + (bid << 9) + tb;
  *(float4*)dst = make_float4(acc0, acc1, acc2, acc3);
}

// ---------------------------------------------------------------------------
// reduce: y[t] = D*u[t] + sum_{c<=m} Pp[(T(m)+c)*512 + (t&511)], m = t>>9
// ---------------------------------------------------------------------------
__global__ __launch_bounds__(256) void reduce_k(const float* __restrict__ Pp,
                                                const float* __restrict__ u,
                                                const float* __restrict__ D,
                                                float* __restrict__ y) {
  int t = blockIdx.x * 256 + threadIdx.x;
  if (t >= L_SEQ) return;
  int m = t >> 9;
  int base = ((m * (m + 1) / 2) << 9) + (t & 511);
  float acc = D[0] * u[t];
  for (int c = 0; c <= m; ++c) acc += Pp[base + (c << 9)];
  y[t] = acc;
}

// ---------------------------------------------------------------------------
// host side. ws layout (bytes):
//   [0, 524288)        per-block Neumann spills (2 x 131072 u16)
//   [524288, 655360)   rt (R^T) 2 planes of 32768 u16
//   [655360, 720896)   gs (S)   2 planes of 16384 u16
//   [720896, 851968)   Kv f32[32768]
//   [851968, 5111808)  Pp f32[2080*512]  (== round-2's proven ws extent)
// ---------------------------------------------------------------------------
extern "C" void kernel_launch(void* const* d_in, const int* in_sizes, int n_in,
                              void* d_out, int out_size, void* d_ws, size_t ws_size,
                              hipStream_t stream) {
  (void)in_sizes; (void)n_in; (void)out_size; (void)ws_size;
  const float* u     = (const float*)d_in[0];
  const float* A     = (const float*)d_in[1];
  const float* B     = (const float*)d_in[2];
  const float* C     = (const float*)d_in[3];
  const float* D     = (const float*)d_in[4];
  const float* lstep = (const float*)d_in[5];
  float* y = (float*)d_out;
  u16* ws = (u16*)d_ws;

  u16* rt = ws + 262144;
  u16* gs = ws + 327680;
  float* Kv = (float*)((char*)d_ws + 720896);
  float* Pp = (float*)((char*)d_ws + 851968);

  (void)hipFuncSetAttribute((const void*)chain_k,
                            hipFuncAttributeMaxDynamicSharedMemorySize, 139264);
  hipLaunchKernelGGL(chain_k, dim3(2), dim3(1024), 139264, stream, A, B, C, lstep, ws);
  hipLaunchKernelGGL(kmat_k, dim3(128), dim3(256), 0, stream, gs, rt, Kv);
  hipLaunchKernelGGL(conv_k, dim3(2080), dim3(128), 0, stream, u, Kv, Pp);
  hipLaunchKernelGGL(reduce_k, dim3(L_SEQ / 256), dim3(256), 0, stream, Pp, u, D, y);
}